// Round 1
// baseline (865.068 us; speedup 1.0000x reference)
//
#include <hip/hip_runtime.h>
#include <hip/hip_bf16.h>
#include <stdint.h>

// MambaConditioningBlock on gfx950.
// B=4, L=2048, D_MODEL=1024, D_INNER=2048, D_STATE=16, DT_RANK=64, D_CONV=4.
// Pipeline:
//  1. k_wt x4   : fp32 weights -> bf16 transposed [N][K] (x-proj padded N 96->128)
//  2. k_ada     : mod = silu(c) @ W_ada + b_ada            [4][3072]
//  3. k_ln      : LayerNorm + (1+scale)/shift -> h_bf      [8192][1024] bf16
//  4. k_gemm<0> : h @ W_in -> xm_T, z_T  (bf16, TRANSPOSED [b][d][t] via C/D-layout 4-row stores)
//  5. k_conv    : causal depthwise conv + silu -> u_T [b][d][t] bf16 + xc [m][d] bf16 (LDS transpose)
//  6. k_gemm<1> : xc @ W_xproj, split-K (grid.z=4) -> part_T [4][128][8192] fp32
//  7. k_xsplit  : reduce 4 partials, split -> dt_bf [m][64], B_T/C_T [b][16][t] fp32
//  8. k_gemm<2> : dt @ W_dt + b_dt, softplus -> delta_T [b][d][t] fp32
//  9. k_scan    : selective scan, thread per (b,d,s), DPP row-16 reduction, fused
//                 (+u*D_skip)*silu(z) epilogue -> y_bf [m][d] bf16
// 10. k_gemm<3> : y @ W_out, epilogue out = x + gate*acc -> d_out fp32

#define L_ 2048
#define DM 1024
#define DI 2048
#define DS 16

typedef __bf16 bf16x8 __attribute__((ext_vector_type(8)));
typedef float f32x4 __attribute__((ext_vector_type(4)));

__device__ __forceinline__ float bf2f(unsigned int u) {
  union { unsigned int i; float f; } c;
  c.i = (u & 0xFFFFu) << 16;
  return c.f;
}
__device__ __forceinline__ unsigned short f2bf(float f) {
  union { float f; unsigned int i; } c; c.f = f;
  unsigned int x = c.i;
  return (unsigned short)((x + 0x7FFFu + ((x >> 16) & 1u)) >> 16);  // RNE
}
__device__ __forceinline__ float silu_f(float v) { return v / (1.f + __expf(-v)); }

// ---- DPP row-16 sum (VALU pipe; avoids DS-pipe ds_swizzle for shfl) ----
template<int CTRL>
__device__ __forceinline__ float dpp_add(float v) {
  union { float f; int i; } c; c.f = v;
  int p = __builtin_amdgcn_update_dpp(0, c.i, CTRL, 0xF, 0xF, true);
  union { int i; float f; } r; r.i = p;
  return v + r.f;
}
__device__ __forceinline__ float row16_sum(float v) {
  v = dpp_add<0xB1>(v);   // quad_perm [1,0,3,2]  (s^1)
  v = dpp_add<0x4E>(v);   // quad_perm [2,3,0,1]  (s^2)
  v = dpp_add<0x141>(v);  // row_half_mirror      (quad<->quad)
  v = dpp_add<0x140>(v);  // row_mirror           (half<->half)
  return v;               // all 16 lanes of the row hold the sum
}

// ---- async global->LDS, 16B per lane (dest = wave-uniform base + lane*16) ----
__device__ __forceinline__ void async_cp16(unsigned short* lds, const unsigned short* g) {
  __builtin_amdgcn_global_load_lds(
      (const __attribute__((address_space(1))) unsigned int*)g,
      (__attribute__((address_space(3))) unsigned int*)lds, 16, 0, 0);
}

// =================== weight transpose+convert: src[K][N] fp32 -> dst[NP][K] bf16 ===================
__global__ __launch_bounds__(256) void k_wt(const float* __restrict__ src,
                                            unsigned short* __restrict__ dst,
                                            int K, int N, int NP) {
  __shared__ float tile[32][33];
  const int kb = blockIdx.x * 32, nb = blockIdx.y * 32;
  const int tx = threadIdx.x & 31, ty = threadIdx.x >> 5;
#pragma unroll
  for (int i = 0; i < 4; i++) {
    int k = kb + ty + 8 * i, n = nb + tx;
    float v = 0.f;
    if (k < K && n < N) v = src[(size_t)k * N + n];
    tile[ty + 8 * i][tx] = v;
  }
  __syncthreads();
#pragma unroll
  for (int i = 0; i < 4; i++) {
    int n = nb + ty + 8 * i, k = kb + tx;
    if (n < NP && k < K) dst[(size_t)n * K + k] = f2bf(tile[tx][ty + 8 * i]);
  }
}

// =================== mod = silu(c) @ W_ada + b_ada ===================
__global__ __launch_bounds__(256) void k_ada(const float* __restrict__ c,
                                             const float* __restrict__ W,
                                             const float* __restrict__ bias,
                                             float* __restrict__ mod) {
  __shared__ float sc[DM];
  const int b = blockIdx.y, tid = threadIdx.x;
  for (int k = tid; k < DM; k += 256) sc[k] = silu_f(c[b * DM + k]);
  __syncthreads();
  const int j = blockIdx.x * 256 + tid;
  float acc = bias[j];
#pragma unroll 8
  for (int k = 0; k < DM; k++) acc += sc[k] * W[(size_t)k * 3072 + j];
  mod[b * 3072 + j] = acc;
}

// =================== LayerNorm + adaLN modulation -> bf16 ===================
__global__ __launch_bounds__(256) void k_ln(const float* __restrict__ x,
                                            const float* __restrict__ mod,
                                            unsigned short* __restrict__ h) {
  const int row = blockIdx.x, b = row >> 11, tid = threadIdx.x;
  const float4 v = ((const float4*)(x + (size_t)row * DM))[tid];
  float s = v.x + v.y + v.z + v.w;
  float ss = v.x * v.x + v.y * v.y + v.z * v.z + v.w * v.w;
#pragma unroll
  for (int off = 32; off; off >>= 1) { s += __shfl_down(s, off); ss += __shfl_down(ss, off); }
  __shared__ float red[10];
  const int wv = tid >> 6, ln = tid & 63;
  if (ln == 0) { red[wv] = s; red[4 + wv] = ss; }
  __syncthreads();
  if (tid == 0) {
    float st = red[0] + red[1] + red[2] + red[3];
    float sst = red[4] + red[5] + red[6] + red[7];
    float mu = st * (1.f / DM);
    red[8] = mu;
    red[9] = rsqrtf(sst * (1.f / DM) - mu * mu + 1e-6f);
  }
  __syncthreads();
  const float mu = red[8], rstd = red[9];
  const int ccol = tid * 4;
  const float4 sc = *(const float4*)(mod + b * 3072 + ccol);
  const float4 sh = *(const float4*)(mod + b * 3072 + DM + ccol);
  uint2 p;
  p.x = (unsigned)f2bf((v.x - mu) * rstd * (1.f + sc.x) + sh.x) |
        ((unsigned)f2bf((v.y - mu) * rstd * (1.f + sc.y) + sh.y) << 16);
  p.y = (unsigned)f2bf((v.z - mu) * rstd * (1.f + sc.z) + sh.z) |
        ((unsigned)f2bf((v.w - mu) * rstd * (1.f + sc.w) + sh.w) << 16);
  *(uint2*)(h + (size_t)row * DM + ccol) = p;
}

// =================== bf16 MFMA GEMM, 128x128 tile, m97 structure ===================
// C[M,N] = A[M,K] @ Bt[N,K]^T, both bf16 row-major with k contiguous.
// 4 waves (2x2), each 64x64 via 4x4 grid of mfma_f32_16x16x32_bf16.
struct GArgs {
  const unsigned short* A;
  const unsigned short* Bt;
  int lda, ldb, klen;
  float* f0;
  unsigned short* h0;
  unsigned short* h1;
  const float* c0;
  const float* c1;
};

template<int EPI>
__global__ __launch_bounds__(256, 2) void k_gemm(GArgs g) {
  __shared__ unsigned short sA[128 * 32];
  __shared__ unsigned short sB[128 * 32];
  const int tid = threadIdx.x;
  const int w = tid >> 6, lane = tid & 63;
  const int m0 = blockIdx.x * 128, n0 = blockIdx.y * 128;
  const int kstart = blockIdx.z * g.klen;
  // staging: chunk w and w+4 per wave; each chunk = 16 rows x 32 cols = 1KB LDS
  const int r4 = lane >> 2;            // row within chunk
  const int c8 = (lane & 3) * 8;       // k-element offset
  const int rowA0 = w * 16 + r4, rowA1 = (w + 4) * 16 + r4;
  const unsigned short* gA0 = g.A + (size_t)(m0 + rowA0) * g.lda + kstart + c8;
  const unsigned short* gA1 = g.A + (size_t)(m0 + rowA1) * g.lda + kstart + c8;
  const unsigned short* gB0 = g.Bt + (size_t)(n0 + rowA0) * g.ldb + kstart + c8;
  const unsigned short* gB1 = g.Bt + (size_t)(n0 + rowA1) * g.ldb + kstart + c8;
  unsigned short* lA0 = sA + w * 512;
  unsigned short* lA1 = sA + (w + 4) * 512;
  unsigned short* lB0 = sB + w * 512;
  unsigned short* lB1 = sB + (w + 4) * 512;
  const int mw = (w & 1) * 64, nw = (w >> 1) * 64;
  const int row16 = lane & 15, k8 = (lane >> 4) * 8;
  f32x4 acc[4][4] = {};
  for (int kk = 0; kk < g.klen; kk += 32) {
    async_cp16(lA0, gA0); async_cp16(lA1, gA1);
    async_cp16(lB0, gB0); async_cp16(lB1, gB1);
    gA0 += 32; gA1 += 32; gB0 += 32; gB1 += 32;
    __syncthreads();  // compiler emits vmcnt(0) drain before barrier
    bf16x8 av[4], bv[4];
#pragma unroll
    for (int i = 0; i < 4; i++)
      av[i] = *(const bf16x8*)(sA + (mw + 16 * i + row16) * 32 + k8);
#pragma unroll
    for (int j = 0; j < 4; j++)
      bv[j] = *(const bf16x8*)(sB + (nw + 16 * j + row16) * 32 + k8);
#pragma unroll
    for (int i = 0; i < 4; i++)
#pragma unroll
      for (int j = 0; j < 4; j++)
        acc[i][j] = __builtin_amdgcn_mfma_f32_16x16x32_bf16(av[i], bv[j], acc[i][j], 0, 0, 0);
    __syncthreads();
  }
  // epilogue: lane holds rows m..m+3 (consecutive!) for col n -> transposed stores are contiguous
  const int qr = (lane >> 4) * 4, cn = lane & 15;
#pragma unroll
  for (int i = 0; i < 4; i++) {
    const int m = m0 + mw + 16 * i + qr;
    const int b = m >> 11, t = m & 2047;
#pragma unroll
    for (int j = 0; j < 4; j++) {
      const int n = n0 + nw + 16 * j + cn;
      f32x4 v = acc[i][j];
      if constexpr (EPI == 0) {
        // in-proj: split xm / z, both bf16 transposed [b][d][t]
        uint2 p;
        p.x = (unsigned)f2bf(v[0]) | ((unsigned)f2bf(v[1]) << 16);
        p.y = (unsigned)f2bf(v[2]) | ((unsigned)f2bf(v[3]) << 16);
        unsigned short* dst = (n < DI)
            ? g.h0 + ((size_t)b << 22) + (size_t)n * L_ + t
            : g.h1 + ((size_t)b << 22) + (size_t)(n - DI) * L_ + t;
        *(uint2*)dst = p;
      } else if constexpr (EPI == 1) {
        // x-proj split-K partial, transposed [z][n][m] fp32
        *(f32x4*)(g.f0 + ((size_t)(blockIdx.z * 128 + n)) * 8192 + m) = v;
      } else if constexpr (EPI == 2) {
        // dt-proj: +b_dt, softplus, -> delta_T [b][d][t] fp32
        const float bn = g.c0[n];
        f32x4 o;
#pragma unroll
        for (int r = 0; r < 4; r++) {
          float xx = v[r] + bn;
          o[r] = (xx > 15.f) ? xx : __logf(1.f + __expf(xx));
        }
        *(f32x4*)(g.f0 + ((size_t)b << 22) + (size_t)n * L_ + t) = o;
      } else {
        // out-proj: out = x + gate * acc
        const float gate = g.c1[b * 3072 + 2048 + n];
#pragma unroll
        for (int r = 0; r < 4; r++) {
          size_t idx = (size_t)(m + r) * DM + n;
          g.f0[idx] = g.c0[idx] + gate * v[r];
        }
      }
    }
  }
}

// =================== causal depthwise conv (k=4) + silu ===================
// reads xm_T [b][d][t]; writes u_T [b][d][t] bf16 and xc [m][d] bf16 (via LDS transpose)
__global__ __launch_bounds__(256) void k_conv(const unsigned short* __restrict__ xmT,
                                              const float* __restrict__ conv_w,
                                              const float* __restrict__ conv_b,
                                              unsigned short* __restrict__ uT,
                                              unsigned short* __restrict__ xc) {
  __shared__ unsigned short sT[32][33];
  const int b = blockIdx.z, t0 = blockIdx.x * 32, d0 = blockIdx.y * 32;
  const int tid = threadIdx.x;
  const int tq = tid & 7, dx = tid >> 3;  // 8 t-groups x 32 d
  const int d = d0 + dx;
  const int tg = t0 + tq * 4;
  const unsigned short* src = xmT + ((size_t)b << 22) + (size_t)d * L_;
  uint2 wA = make_uint2(0u, 0u);
  if (tg >= 4) wA = *(const uint2*)(src + tg - 4);
  const uint2 wB = *(const uint2*)(src + tg);
  float xw[8];
  xw[0] = bf2f(wA.x); xw[1] = bf2f(wA.x >> 16);
  xw[2] = bf2f(wA.y); xw[3] = bf2f(wA.y >> 16);
  xw[4] = bf2f(wB.x); xw[5] = bf2f(wB.x >> 16);
  xw[6] = bf2f(wB.y); xw[7] = bf2f(wB.y >> 16);
  const float w0 = conv_w[d * 4 + 0], w1 = conv_w[d * 4 + 1];
  const float w2 = conv_w[d * 4 + 2], w3 = conv_w[d * 4 + 3];
  const float cb = conv_b[d];
  unsigned short rb[4];
#pragma unroll
  for (int i = 0; i < 4; i++) {
    float a = cb + w0 * xw[i + 1] + w1 * xw[i + 2] + w2 * xw[i + 3] + w3 * xw[i + 4];
    rb[i] = f2bf(silu_f(a));
  }
  uint2 p;
  p.x = (unsigned)rb[0] | ((unsigned)rb[1] << 16);
  p.y = (unsigned)rb[2] | ((unsigned)rb[3] << 16);
  *(uint2*)(uT + ((size_t)b << 22) + (size_t)d * L_ + tg) = p;
  const int tl0 = tq * 4;
#pragma unroll
  for (int i = 0; i < 4; i++) sT[tl0 + i][dx] = rb[i];
  __syncthreads();
  const int dl2 = tid & 31, tb2 = tid >> 5;
#pragma unroll
  for (int i = 0; i < 4; i++) {
    int tl = tb2 + 8 * i;
    xc[((size_t)b * L_ + t0 + tl) * (size_t)DI + d0 + dl2] = sT[tl][dl2];
  }
}

// =================== reduce split-K partials, split dt/B/C ===================
__global__ __launch_bounds__(256) void k_xsplit(const float* __restrict__ pt,
                                                unsigned short* __restrict__ dtb,
                                                float* __restrict__ BTo,
                                                float* __restrict__ CTo) {
  const int bx = blockIdx.x;
  const int n = bx >> 5;                              // 0..95
  const int m = ((bx & 31) << 8) + threadIdx.x;       // 0..8191
  float v = pt[(size_t)n * 8192 + m] + pt[(size_t)(128 + n) * 8192 + m] +
            pt[(size_t)(256 + n) * 8192 + m] + pt[(size_t)(384 + n) * 8192 + m];
  const int b = m >> 11, t = m & 2047;
  if (n < 64) dtb[(size_t)m * 64 + n] = f2bf(v);
  else if (n < 80) BTo[b * (DS * L_) + (n - 64) * L_ + t] = v;
  else CTo[b * (DS * L_) + (n - 80) * L_ + t] = v;
}

// =================== selective scan: thread per (b,d,s) ===================
__global__ __launch_bounds__(256) void k_scan(const float* __restrict__ dT,
                                              const unsigned short* __restrict__ uT,
                                              const unsigned short* __restrict__ zT,
                                              const float* __restrict__ BT,
                                              const float* __restrict__ CT,
                                              const float* __restrict__ A_log,
                                              const float* __restrict__ Dsk,
                                              unsigned short* __restrict__ y) {
  const int b = blockIdx.y;
  const int d0 = blockIdx.x * 16;
  const int tid = threadIdx.x, dl = tid >> 4, s = tid & 15;
  const int d = d0 + dl;
  const float* dp = dT + ((size_t)b << 22) + (size_t)d * L_;
  const unsigned short* up = uT + ((size_t)b << 22) + (size_t)d * L_;
  const unsigned short* zp = zT + ((size_t)b << 22) + (size_t)d * L_;
  const float* bp = BT + b * (DS * L_) + s * L_;
  const float* cp = CT + b * (DS * L_) + s * L_;
  const float Av = -__expf(A_log[d * DS + s]);
  const float dsk = Dsk[d];
  unsigned short* yp = y + ((size_t)b * L_) * DI + d;
  float h = 0.f;
  for (int t0 = 0; t0 < L_; t0 += 4) {
    const f32x4 dv4 = *(const f32x4*)(dp + t0);
    const f32x4 b4 = *(const f32x4*)(bp + t0);
    const f32x4 c4 = *(const f32x4*)(cp + t0);
    const uint2 ur = *(const uint2*)(up + t0);
    const float uv0 = bf2f(ur.x), uv1 = bf2f(ur.x >> 16);
    const float uv2 = bf2f(ur.y), uv3 = bf2f(ur.y >> 16);
    float a, yq0, yq1, yq2, yq3;
    a = __expf(dv4[0] * Av); h = a * h + (dv4[0] * uv0) * b4[0]; yq0 = row16_sum(h * c4[0]);
    a = __expf(dv4[1] * Av); h = a * h + (dv4[1] * uv1) * b4[1]; yq1 = row16_sum(h * c4[1]);
    a = __expf(dv4[2] * Av); h = a * h + (dv4[2] * uv2) * b4[2]; yq2 = row16_sum(h * c4[2]);
    a = __expf(dv4[3] * Av); h = a * h + (dv4[3] * uv3) * b4[3]; yq3 = row16_sum(h * c4[3]);
    if (s < 4) {  // 4 lanes per row handle the 4 buffered steps' epilogues
      const uint2 zr = *(const uint2*)(zp + t0);
      const unsigned zsel = (s < 2) ? zr.x : zr.y;
      const float zv = bf2f((s & 1) ? (zsel >> 16) : zsel);
      const float uv = (s == 0) ? uv0 : (s == 1) ? uv1 : (s == 2) ? uv2 : uv3;
      const float yv = (s == 0) ? yq0 : (s == 1) ? yq1 : (s == 2) ? yq2 : yq3;
      const float yt = (yv + uv * dsk) * silu_f(zv);
      yp[(size_t)(t0 + s) * DI] = f2bf(yt);
    }
  }
}

// =================== launch ===================
extern "C" void kernel_launch(void* const* d_in, const int* in_sizes, int n_in,
                              void* d_out, int out_size, void* d_ws, size_t ws_size,
                              hipStream_t stream) {
  const float* x      = (const float*)d_in[0];
  const float* c      = (const float*)d_in[1];
  const float* W_in   = (const float*)d_in[2];
  const float* conv_w = (const float*)d_in[3];
  const float* conv_b = (const float*)d_in[4];
  const float* W_xp   = (const float*)d_in[5];
  const float* W_dt   = (const float*)d_in[6];
  const float* b_dt   = (const float*)d_in[7];
  const float* A_log  = (const float*)d_in[8];
  const float* D_skip = (const float*)d_in[9];
  const float* W_out  = (const float*)d_in[10];
  const float* W_ada  = (const float*)d_in[11];
  const float* b_ada  = (const float*)d_in[12];
  float* out = (float*)d_out;

  char* ws = (char*)d_ws;
  size_t off = 0;
  auto take = [&](size_t bytes) {
    char* p = ws + off;
    off += (bytes + 255) & ~(size_t)255;
    return p;
  };
  float* mod             = (float*)take((size_t)4 * 3072 * 4);
  unsigned short* Wt_in  = (unsigned short*)take((size_t)4096 * 1024 * 2);
  unsigned short* Wt_out = (unsigned short*)take((size_t)1024 * 2048 * 2);
  unsigned short* Wt_xp  = (unsigned short*)take((size_t)128 * 2048 * 2);
  unsigned short* Wt_dt  = (unsigned short*)take((size_t)2048 * 64 * 2);
  unsigned short* h_bf   = (unsigned short*)take((size_t)8192 * 1024 * 2);  // reused as part_T
  unsigned short* xm_T   = (unsigned short*)take((size_t)4 * 2048 * 2048 * 2);  // reused as y_bf
  unsigned short* z_T    = (unsigned short*)take((size_t)4 * 2048 * 2048 * 2);
  unsigned short* u_T    = (unsigned short*)take((size_t)4 * 2048 * 2048 * 2);
  unsigned short* xc     = (unsigned short*)take((size_t)8192 * 2048 * 2);
  float* delta_T         = (float*)take((size_t)4 * 2048 * 2048 * 4);
  unsigned short* dt_bf  = (unsigned short*)take((size_t)8192 * 64 * 2);
  float* B_T             = (float*)take((size_t)4 * 16 * 2048 * 4);
  float* C_T             = (float*)take((size_t)4 * 16 * 2048 * 4);
  float* part_T = (float*)h_bf;       // 4*128*8192*4 B == h_bf size; h_bf dead after in-proj
  unsigned short* y_bf = xm_T;        // xm_T dead after conv

  // 1. weight convert+transpose
  k_wt<<<dim3(32, 128), 256, 0, stream>>>(W_in, Wt_in, 1024, 4096, 4096);
  k_wt<<<dim3(64, 32), 256, 0, stream>>>(W_out, Wt_out, 2048, 1024, 1024);
  k_wt<<<dim3(64, 4), 256, 0, stream>>>(W_xp, Wt_xp, 2048, 96, 128);  // zero-padded rows 96..127
  k_wt<<<dim3(2, 64), 256, 0, stream>>>(W_dt, Wt_dt, 64, 2048, 2048);
  // 2. conditioning
  k_ada<<<dim3(12, 4), 256, 0, stream>>>(c, W_ada, b_ada, mod);
  // 3. LN + modulation
  k_ln<<<8192, 256, 0, stream>>>(x, mod, h_bf);
  // 4. in-proj
  GArgs a1{h_bf, Wt_in, 1024, 1024, 1024, nullptr, xm_T, z_T, nullptr, nullptr};
  k_gemm<0><<<dim3(64, 32), 256, 0, stream>>>(a1);
  // 5. conv + silu
  k_conv<<<dim3(64, 64, 4), 256, 0, stream>>>(xm_T, conv_w, conv_b, u_T, xc);
  // 6. x-proj (split-K over grid.z)
  GArgs a2{xc, Wt_xp, 2048, 2048, 512, part_T, nullptr, nullptr, nullptr, nullptr};
  k_gemm<1><<<dim3(64, 1, 4), 256, 0, stream>>>(a2);
  // 7. reduce + split
  k_xsplit<<<3072, 256, 0, stream>>>(part_T, dt_bf, B_T, C_T);
  // 8. dt-proj + softplus
  GArgs a3{dt_bf, Wt_dt, 64, 64, 64, delta_T, nullptr, nullptr, b_dt, nullptr};
  k_gemm<2><<<dim3(64, 16), 256, 0, stream>>>(a3);
  // 9. selective scan (fused skip + silu(z) gate)
  k_scan<<<dim3(128, 4), 256, 0, stream>>>(delta_T, u_T, z_T, B_T, C_T, A_log, D_skip, y_bf);
  // 10. out-proj + residual + gate
  GArgs a4{y_bf, Wt_out, 2048, 2048, 2048, out, nullptr, nullptr, x, mod};
  k_gemm<3><<<dim3(64, 8), 256, 0, stream>>>(a4);
}